// Round 8
// baseline (342.951 us; speedup 1.0000x reference)
//
#include <hip/hip_runtime.h>
#include <math.h>

#define B_  2048
#define T_  200

typedef short short8 __attribute__((ext_vector_type(8)));
typedef float f32x4  __attribute__((ext_vector_type(4)));

__device__ __forceinline__ unsigned short f2bf_rne(float x) {
    unsigned u = __float_as_uint(x);
    unsigned r = u + 0x7FFFu + ((u >> 16) & 1u);
    return (unsigned short)(r >> 16);
}
__device__ __forceinline__ float bf2f(unsigned short h) {
    return __uint_as_float(((unsigned)h) << 16);
}
__device__ __forceinline__ void split2(float x, unsigned short& hi, unsigned short& lo) {
    hi = f2bf_rne(x); lo = f2bf_rne(x - bf2f(hi));
}

// One block (4 waves) per batch element b. Barrier-free 13-m-tile loop.
// R8 = R7 + occupancy push: (256,2)->(256,3). At (256,2) total regs ~192
// (120 arch + 72 W2-frag) -> 2 waves/SIMD, 80% stall. 3 waves needs <=170:
//   - ca2 loads moved between Dense1 and Dense2 (-12 peak; latency hides
//     under Dense2's ds_reads+MFMAs)
//   - bb1 regs -> in-place fold into s_b1p (lane-safe), read per tile (-5)
//   - A-frag build first in tile (ends old-pk live range before new issues)
// LDS 52224*3 = 153KB < 160KB -> 3 blocks/CU if regs fit. Confirmation:
// Occupancy ~30%, WRITE_SIZE stays ~0.5MB. Spill => WRITE_SIZE balloons.
__global__ __launch_bounds__(256, 3)
void att_kernel(const float* __restrict__ q,
                const float* __restrict__ k,
                const float* __restrict__ v,
                const float* __restrict__ W1,
                const float* __restrict__ b1,
                const float* __restrict__ a1,
                const float* __restrict__ W2,
                const float* __restrict__ b2,
                const float* __restrict__ a2,
                const float* __restrict__ Wf,
                const float* __restrict__ bf,
                float* __restrict__ out)
{
    const int b    = blockIdx.x;
    const int tid  = threadIdx.x;
    const int lane = tid & 63;
    const int wv   = __builtin_amdgcn_readfirstlane(tid >> 6);
    const int ncl  = lane & 15;
    const int q4   = lane >> 4;
    const int kq   = q4 * 8;

    __shared__ unsigned short s_wqhi[80 * 72];               // 11.5 KB
    __shared__ unsigned short s_wqlo[80 * 72];               // 11.5 KB
    __shared__ __align__(16) unsigned short s_h1[2 * 64 * 104]; // 26 KB, unioned
    __shared__ float s_q[64];
    __shared__ float s_b1p[240];   // base1 partials; [0..79] folded to full base1
    __shared__ float s_logits[256];

    unsigned short* s_h1hi = s_h1;
    unsigned short* s_h1lo = s_h1 + 64 * 104;
    // softmax/v-sum scratch aliases s_h1 (dead after the tile loop):
    float*  u_w   = (float*)s_h1;                 // [256]  bytes 0..1023
    float4* u_acc = (float4*)(s_h1 + 512);        // [256]  bytes 1024..5119
    float*  u_red = (float*)(s_h1 + 2560);        // [8]    bytes 5120..5151

    const float* kb = k + (size_t)b * T_ * 64;
    const float* vb = v + (size_t)b * T_ * 64;

    // ---- first-tile k prefetch (HBM-cold): issued first; everything below
    // up to the first consume runs in its shadow. mt = wv < 4 -> trow < 64.
    float4 pk0, pk1, pk2, pk3;
    {
        const float4* kr = (const float4*)(kb + (wv * 16 + ncl) * 64);
        pk0 = kr[q4 * 2];     pk1 = kr[q4 * 2 + 1];
        pk2 = kr[8 + q4 * 2]; pk3 = kr[8 + q4 * 2 + 1];
    }

    if (tid < 64) s_q[tid] = q[b * 64 + tid];

    // ---- global-only prologue work, BEFORE barrier 1 (hides under q/k loads)
    for (int idx = tid; idx < 1024; idx += 256) {   // zero h1 cols 80..95 (K-pad)
        const int r = idx >> 4, c = 80 + (idx & 15);
        s_h1hi[r * 104 + c] = 0;
        s_h1lo[r * 104 + c] = 0;
    }
    // W2 B-fragments into registers (built from L2, once per block)
    short8 w2h[3][3], w2l[3][3];
    #pragma unroll
    for (int nt = 0; nt < 3; ++nt) {
        const int n = nt * 16 + ncl;
        #pragma unroll
        for (int c = 0; c < 3; ++c) {
            short8 hh, ll;
            #pragma unroll
            for (int jj = 0; jj < 8; ++jj) {
                const int kk = c * 32 + kq + jj;
                const float x = (kk < 80 && n < 40) ? W2[kk * 40 + n] : 0.f;
                unsigned short hi, lo; split2(x, hi, lo);
                hh[jj] = (short)hi; ll[jj] = (short)lo;
            }
            w2h[nt][c] = hh; w2l[nt][c] = ll;
        }
    }
    float wf3[3], b23[3];
    #pragma unroll
    for (int nt = 0; nt < 3; ++nt) {
        const int n = nt * 16 + ncl;
        wf3[nt] = (n < 40) ? Wf[n] : 0.f;
        b23[nt] = (n < 40) ? b2[n] : 0.f;
    }
    const float bfv = bf[0];

    __syncthreads();   // B1: s_q (and pad-zero) visible

    // ---- q-dependent prologue: per-b wq (split bf16, B-layout [j][kk]) + base1
    for (int idx = tid; idx < 5120; idx += 256) {
        const int kk = idx / 80, j = idx - kk * 80;
        const float x = W1[5120 + idx] - W1[10240 + idx] + s_q[kk] * W1[15360 + idx];
        unsigned short hi, lo; split2(x, hi, lo);
        s_wqhi[j * 72 + kk] = hi;
        s_wqlo[j * 72 + kk] = lo;
    }
    // base1 partials: 3 k-chunks of <=22, FIXED trip count -> fully unrolled,
    // all loads independent (clamped index, predicated contribution)
    if (tid < 240) {
        const int part = tid / 80;          // 0,1,2
        const int j    = tid - part * 80;
        const int k0   = part * 22;         // 0,22,44
        float s = 0.f;
        #pragma unroll
        for (int kk = 0; kk < 22; ++kk) {
            const int i  = k0 + kk;
            const int ic = (i < 64) ? i : 63;
            const float w = W1[ic * 80 + j] + W1[10240 + ic * 80 + j];
            s += (i < 64) ? s_q[ic] * w : 0.f;
        }
        s_b1p[tid] = s;
    }
    __syncthreads();   // B2: s_wq + s_b1p visible

    // in-place fold: s_b1p[j] <- b1[j] + partial0 + partial1 + partial2.
    // Lane-safe: slot j (j<80) is read only by thread j before this write.
    if (tid < 80) {
        s_b1p[tid] = b1[tid] + s_b1p[tid] + s_b1p[80 + tid] + s_b1p[160 + tid];
    }
    __syncthreads();   // B2b: folded base1 visible

    // ---- barrier-free tile loop: wave wv owns m-tiles wv, wv+4, wv+8, wv+12
    const int h1row = (wv * 16 + ncl) * 104;
    for (int mt = wv; mt < 13; mt += 4) {
        // consume prefetched k FIRST -> A-fragments; ends old-pk live range
        const float a0v[8] = {pk0.x, pk0.y, pk0.z, pk0.w, pk1.x, pk1.y, pk1.z, pk1.w};
        const float a1v[8] = {pk2.x, pk2.y, pk2.z, pk2.w, pk3.x, pk3.y, pk3.z, pk3.w};
        short8 ahi0, alo0, ahi1, alo1;
        #pragma unroll
        for (int jj = 0; jj < 8; ++jj) {
            unsigned short h, l;
            split2(a0v[jj], h, l); ahi0[jj] = (short)h; alo0[jj] = (short)l;
            split2(a1v[jj], h, l); ahi1[jj] = (short)h; alo1[jj] = (short)l;
        }

        // issue next-tile k loads UNCONDITIONALLY (clamped row; extra last-iter
        // load is a harmless cache hit). Named scalars -> SSA.
        {
            int trow_n = (mt + 4) * 16 + ncl; if (trow_n > T_ - 1) trow_n = T_ - 1;
            const float4* kr = (const float4*)(kb + trow_n * 64);
            pk0 = kr[q4 * 2];     pk1 = kr[q4 * 2 + 1];
            pk2 = kr[8 + q4 * 2]; pk3 = kr[8 + q4 * 2 + 1];
        }

        // current-tile a1 coefficients (L2/L3-hot); consumed in Dense1 epilogue
        float ca1[5][4];
        #pragma unroll
        for (int nt = 0; nt < 5; ++nt) {
            #pragma unroll
            for (int r = 0; r < 4; ++r) {
                int t = mt * 16 + q4 * 4 + r; if (t > T_ - 1) t = T_ - 1;
                ca1[nt][r] = a1[t * 80 + nt * 16 + ncl];
            }
        }

        // Dense1 MFMA + PReLU1 epilogue -> h1 (wave-local LDS round-trip)
        #pragma unroll
        for (int nt = 0; nt < 5; ++nt) {
            const int n = nt * 16 + ncl;
            const short8 bhi0 = *(const short8*)&s_wqhi[n * 72 + kq];
            const short8 bhi1 = *(const short8*)&s_wqhi[n * 72 + 32 + kq];
            const short8 blo0 = *(const short8*)&s_wqlo[n * 72 + kq];
            const short8 blo1 = *(const short8*)&s_wqlo[n * 72 + 32 + kq];
            f32x4 acc = {0.f, 0.f, 0.f, 0.f};
            acc = __builtin_amdgcn_mfma_f32_16x16x32_bf16(ahi0, blo0, acc, 0, 0, 0);
            acc = __builtin_amdgcn_mfma_f32_16x16x32_bf16(alo0, bhi0, acc, 0, 0, 0);
            acc = __builtin_amdgcn_mfma_f32_16x16x32_bf16(ahi1, blo1, acc, 0, 0, 0);
            acc = __builtin_amdgcn_mfma_f32_16x16x32_bf16(alo1, bhi1, acc, 0, 0, 0);
            acc = __builtin_amdgcn_mfma_f32_16x16x32_bf16(ahi0, bhi0, acc, 0, 0, 0);
            acc = __builtin_amdgcn_mfma_f32_16x16x32_bf16(ahi1, bhi1, acc, 0, 0, 0);
            const float bbv = s_b1p[n];
            #pragma unroll
            for (int r = 0; r < 4; ++r) {
                const int rloc = q4 * 4 + r;
                float x = acc[r] + bbv;
                const float al = ca1[nt][r];
                x = x > 0.f ? x : al * x;
                unsigned short hi, lo; split2(x, hi, lo);
                s_h1hi[(wv * 16 + rloc) * 104 + n] = hi;
                s_h1lo[(wv * 16 + rloc) * 104 + n] = lo;
            }
        }

        // current-tile a2 coefficients issued HERE (after Dense1): -12 regs of
        // peak pressure; ~500cyc latency hides under Dense2's ds_reads+MFMAs
        float ca2[3][4];
        #pragma unroll
        for (int nt = 0; nt < 3; ++nt) {
            const int n2 = nt * 16 + ncl;
            #pragma unroll
            for (int r = 0; r < 4; ++r) {
                int t = mt * 16 + q4 * 4 + r; if (t > T_ - 1) t = T_ - 1;
                ca2[nt][r] = (n2 < 40) ? a2[t * 40 + n2] : 0.f;
            }
        }

        // Dense2 MFMA (W2 frags in regs) + PReLU2*Wf epilogue -> logits
        short8 ah[3], al[3];
        #pragma unroll
        for (int c = 0; c < 3; ++c) {
            ah[c] = *(const short8*)&s_h1hi[h1row + c * 32 + kq];
            al[c] = *(const short8*)&s_h1lo[h1row + c * 32 + kq];
        }
        float part[4] = {0.f, 0.f, 0.f, 0.f};
        #pragma unroll
        for (int nt = 0; nt < 3; ++nt) {
            f32x4 acc = {0.f, 0.f, 0.f, 0.f};
            #pragma unroll
            for (int c = 0; c < 3; ++c) {
                acc = __builtin_amdgcn_mfma_f32_16x16x32_bf16(ah[c], w2l[nt][c], acc, 0, 0, 0);
                acc = __builtin_amdgcn_mfma_f32_16x16x32_bf16(al[c], w2h[nt][c], acc, 0, 0, 0);
                acc = __builtin_amdgcn_mfma_f32_16x16x32_bf16(ah[c], w2h[nt][c], acc, 0, 0, 0);
            }
            #pragma unroll
            for (int r = 0; r < 4; ++r) {
                float x = acc[r] + b23[nt];
                const float al2 = ca2[nt][r];
                x = x > 0.f ? x : al2 * x;
                part[r] += x * wf3[nt];
            }
        }
        #pragma unroll
        for (int r = 0; r < 4; ++r) {
            float p = part[r];
            p += __shfl_xor(p, 1, 64);
            p += __shfl_xor(p, 2, 64);
            p += __shfl_xor(p, 4, 64);
            p += __shfl_xor(p, 8, 64);
            part[r] = p;
        }
        if (ncl == 0) {
            #pragma unroll
            for (int r = 0; r < 4; ++r) {
                const int t = mt * 16 + q4 * 4 + r;
                if (t < T_) s_logits[t] = part[r] + bfv;
            }
        }
    }
    __syncthreads();   // logits complete; s_h1 dead -> scratch reuse OK

    // ---- softmax over 200 logits (wave shuffles, 2 barriers)
    float logit = -INFINITY;
    if (tid < T_) logit = s_logits[tid];
    float mred = logit;
    #pragma unroll
    for (int off = 1; off < 64; off <<= 1) mred = fmaxf(mred, __shfl_xor(mred, off, 64));
    if (lane == 0) u_red[wv] = mred;
    __syncthreads();
    const float mx = fmaxf(fmaxf(u_red[0], u_red[1]), fmaxf(u_red[2], u_red[3]));
    const float ew = (tid < T_) ? __expf(logit - mx) : 0.f;
    float ssum = ew;
    #pragma unroll
    for (int off = 1; off < 64; off <<= 1) ssum += __shfl_xor(ssum, off, 64);
    if (lane == 0) u_red[4 + wv] = ssum;
    __syncthreads();
    const float tot = (u_red[4] + u_red[5]) + (u_red[6] + u_red[7]);
    const float inv = 1.0f / tot;
    u_w[tid] = ew * inv;
    __syncthreads();

    // ---- out[b][d] = sum_t w_t * v[b][t][d]
    // fixed 13-trip unrolled loop: all 13 independent global loads can issue
    // together (single latency), u_w reads are LDS-hot. No cross-barrier state.
    const int c4 = tid & 15, g = tid >> 4;
    const float4* vb4 = (const float4*)vb;
    float4 acc4 = {0.f, 0.f, 0.f, 0.f};
    #pragma unroll
    for (int i = 0; i < 13; ++i) {
        const int t = g + i * 16;
        const int tc = (t > T_ - 1) ? (T_ - 1) : t;
        const float wt = (t < T_) ? u_w[t] : 0.f;
        const float4 vv = vb4[tc * 16 + c4];
        acc4.x += wt * vv.x; acc4.y += wt * vv.y;
        acc4.z += wt * vv.z; acc4.w += wt * vv.w;
    }
    u_acc[tid] = acc4;
    __syncthreads();
    if (tid < 64) {
        const float* uf = (const float*)u_acc;
        float s = 0.f;
        #pragma unroll
        for (int gg = 0; gg < 16; ++gg) s += uf[gg * 64 + tid];
        out[b * 64 + tid] = s;
    }
}

extern "C" void kernel_launch(void* const* d_in, const int* in_sizes, int n_in,
                              void* d_out, int out_size, void* d_ws, size_t ws_size,
                              hipStream_t stream) {
    const float* q  = (const float*)d_in[0];
    const float* k  = (const float*)d_in[1];
    const float* v  = (const float*)d_in[2];
    const float* W1 = (const float*)d_in[3];
    const float* b1 = (const float*)d_in[4];
    const float* a1 = (const float*)d_in[5];
    const float* W2 = (const float*)d_in[6];
    const float* b2 = (const float*)d_in[7];
    const float* a2 = (const float*)d_in[8];
    const float* Wf = (const float*)d_in[9];
    const float* bf = (const float*)d_in[10];
    float* out = (float*)d_out;

    hipLaunchKernelGGL(att_kernel, dim3(B_), dim3(256), 0, stream,
                       q, k, v, W1, b1, a1, W2, b2, a2, Wf, bf, out);
}